// Round 1
// baseline (610.037 us; speedup 1.0000x reference)
//
#include <hip/hip_runtime.h>

using short8  = short     __attribute__((ext_vector_type(8)));
using half4   = _Float16  __attribute__((ext_vector_type(4)));
using float4_ = float     __attribute__((ext_vector_type(4)));

__device__ __forceinline__ unsigned short f2bf(float f) {
  union { float f; unsigned u; } v; v.f = f;
  unsigned r = v.u + 0x7fffu + ((v.u >> 16) & 1u);
  return (unsigned short)(r >> 16);
}

// ---------------- LayerNorm: x fp32 (8192x512) -> xn bf16 ----------------
__global__ __launch_bounds__(256, 4) void ln_kernel(
    const float* __restrict__ x, const float* __restrict__ gamma,
    const float* __restrict__ beta, unsigned short* __restrict__ xn) {
  int w = threadIdx.x >> 6, lane = threadIdx.x & 63;
  int row = blockIdx.x * 4 + w;
  const float4_* xr = (const float4_*)(x + row * 512);
  float4_ v0 = xr[lane * 2], v1 = xr[lane * 2 + 1];
  float s = 0.f, ss = 0.f;
#pragma unroll
  for (int e = 0; e < 4; ++e) { s += v0[e] + v1[e]; ss += v0[e]*v0[e] + v1[e]*v1[e]; }
#pragma unroll
  for (int off = 1; off < 64; off <<= 1) { s += __shfl_xor(s, off); ss += __shfl_xor(ss, off); }
  float mu = s * (1.f/512.f);
  float var = ss * (1.f/512.f) - mu*mu;
  float rs = rsqrtf(var + 1e-5f);
  const float4_* gp = (const float4_*)gamma;
  const float4_* bp = (const float4_*)beta;
  float4_ g0 = gp[lane*2], g1 = gp[lane*2+1], b0 = bp[lane*2], b1 = bp[lane*2+1];
  short8 pk;
#pragma unroll
  for (int e = 0; e < 4; ++e) {
    pk[e]   = (short)f2bf((v0[e]-mu)*rs*g0[e] + b0[e]);
    pk[e+4] = (short)f2bf((v1[e]-mu)*rs*g1[e] + b1[e]);
  }
  *(short8*)&xn[row*512 + lane*8] = pk;
}

// ------------- weights fp32 -> bf16 transposed (B^T layouts) -------------
// wt[n][k] for n in [0,1536): n<512 -> Wq[k][n]*0.125 ; else Wkv[k][n-512]
// wot[n][k] = Wout[k][n]
__global__ __launch_bounds__(256, 4) void wconv(
    const float* __restrict__ Wq, const float* __restrict__ Wkv,
    const float* __restrict__ Wout, unsigned short* __restrict__ wt,
    unsigned short* __restrict__ wot) {
  int t = blockIdx.x * 256 + threadIdx.x;
  if (t < 786432) {
    int k = t / 1536, n = t % 1536;
    float v = (n < 512) ? Wq[k*512 + n] * 0.125f : Wkv[k*1024 + (n - 512)];
    wt[n*512 + k] = f2bf(v);
  } else {
    int t2 = t - 786432;
    int k = t2 >> 9, n = t2 & 511;
    wot[n*512 + k] = f2bf(Wout[k*512 + n]);
  }
}

// ---------------- QKV GEMM: xn(8192x512) @ Wt^T -> Q,K (bf16 b,h,n,64), V^T (f16 b,h,64,n)
__global__ __launch_bounds__(256, 2) void qkv_gemm(
    const unsigned short* __restrict__ A, const unsigned short* __restrict__ Bt,
    unsigned short* __restrict__ Qs, unsigned short* __restrict__ Kb,
    _Float16* __restrict__ Vt) {
  __shared__ unsigned short lA[128*32];
  __shared__ unsigned short lB[128*32];
  int bid = blockIdx.x;
  int tm = bid & 63, tn = bid >> 6;           // 64 x 12
  int m0 = tm * 128, n0 = tn * 128;
  int tid = threadIdx.x, lane = tid & 63, w = tid >> 6;
  int lrow = lane & 15, lgrp = lane >> 4;
  int wr = w >> 1, wc = w & 1;
  int r0 = tid >> 2, c0 = tid & 3;
  float4_ acc[4][4];
#pragma unroll
  for (int mi = 0; mi < 4; ++mi)
#pragma unroll
    for (int ni = 0; ni < 4; ++ni) acc[mi][ni] = (float4_){0.f,0.f,0.f,0.f};

  for (int k0 = 0; k0 < 512; k0 += 32) {
    short8 a0 = *(const short8*)&A[(m0 + r0)*512 + k0 + c0*8];
    short8 a1 = *(const short8*)&A[(m0 + 64 + r0)*512 + k0 + c0*8];
    short8 b0 = *(const short8*)&Bt[(n0 + r0)*512 + k0 + c0*8];
    short8 b1 = *(const short8*)&Bt[(n0 + 64 + r0)*512 + k0 + c0*8];
    __syncthreads();
    *(short8*)&lA[tid*8] = a0; *(short8*)&lA[(tid+256)*8] = a1;
    *(short8*)&lB[tid*8] = b0; *(short8*)&lB[(tid+256)*8] = b1;
    __syncthreads();
    short8 af[4], bfr[4];
#pragma unroll
    for (int mi = 0; mi < 4; ++mi) af[mi]  = *(const short8*)&lA[(wr*64 + mi*16 + lrow)*32 + lgrp*8];
#pragma unroll
    for (int ni = 0; ni < 4; ++ni) bfr[ni] = *(const short8*)&lB[(wc*64 + ni*16 + lrow)*32 + lgrp*8];
#pragma unroll
    for (int mi = 0; mi < 4; ++mi)
#pragma unroll
      for (int ni = 0; ni < 4; ++ni)
        acc[mi][ni] = __builtin_amdgcn_mfma_f32_16x16x32_bf16(af[mi], bfr[ni], acc[mi][ni], 0, 0, 0);
  }
  // epilogue: scatter to attention layouts
#pragma unroll
  for (int mi = 0; mi < 4; ++mi) {
#pragma unroll
    for (int ni = 0; ni < 4; ++ni) {
      int col = n0 + wc*64 + ni*16 + lrow;
#pragma unroll
      for (int r = 0; r < 4; ++r) {
        int row = m0 + wr*64 + mi*16 + lgrp*4 + r;
        float v = acc[mi][ni][r];
        int b = row >> 11, i = row & 2047;
        if (col < 1024) {
          unsigned short* dst = (col < 512) ? Qs : Kb;
          int c = col & 511;
          dst[(((b<<3) + (c>>6))*2048 + i)*64 + (c & 63)] = f2bf(v);
        } else {
          int c = col - 1024;
          Vt[(((b<<3) + (c>>6))*64 + (c & 63))*2048 + i] = (_Float16)v;
        }
      }
    }
  }
}

// ---------------- fused talking-heads attention ----------------
// block: (b, 16-row i-tile). 4 waves, wave w owns j-tiles jt === w (mod 4).
// pass1: S^T = mfma(K,Q) per head, premix (VALU), online m/l per output head.
// pass2: recompute, normalize exactly, postmix, PV via mfma_16x16x16_f16.
__global__ __launch_bounds__(256, 1) void attn_kernel(
    const unsigned short* __restrict__ Qs, const unsigned short* __restrict__ Kb,
    const _Float16* __restrict__ Vt, const float* __restrict__ mixp,
    const float* __restrict__ mixq, unsigned short* __restrict__ AO) {
  int bid = blockIdx.x;
  int xcd = bid & 7;
  int b = xcd >> 1;
  int it = ((xcd & 1) << 6) | (bid >> 3);
  int i0 = it << 4;
  int tid = threadIdx.x, w = tid >> 6, lane = tid & 63;
  int lrow = lane & 15, lgrp = lane >> 4;

  __shared__ float Lm[4][8][16];
  __shared__ float Ll[4][8][16];
  __shared__ float Ob[8][64][16];

  // persistent Q fragments (B operand: col=i, k=d)
  short8 qf[8][2];
#pragma unroll
  for (int h = 0; h < 8; ++h) {
    int base = (((b<<3)+h)*2048 + i0 + lrow)*64 + lgrp*8;
#pragma unroll
    for (int t = 0; t < 2; ++t) qf[h][t] = *(const short8*)&Qs[base + t*32];
  }

  float m_[8], l_[8];
#pragma unroll
  for (int g = 0; g < 8; ++g) { m_[g] = -1e30f; l_[g] = 0.f; }

  // ---------------- PASS 1: stats ----------------
  for (int jt = w; jt < 128; jt += 4) {
    int j0 = jt << 4;
    short8 kfr[8][2];
#pragma unroll
    for (int h = 0; h < 8; ++h) {
      int base = (((b<<3)+h)*2048 + j0 + lrow)*64 + lgrp*8;
      kfr[h][0] = *(const short8*)&Kb[base];
      kfr[h][1] = *(const short8*)&Kb[base + 32];
    }
    float4_ S[8];
#pragma unroll
    for (int h = 0; h < 8; ++h) {
      float4_ z = {0.f,0.f,0.f,0.f};
      z = __builtin_amdgcn_mfma_f32_16x16x32_bf16(kfr[h][0], qf[h][0], z, 0, 0, 0);
      S[h] = __builtin_amdgcn_mfma_f32_16x16x32_bf16(kfr[h][1], qf[h][1], z, 0, 0, 0);
    }
#pragma unroll
    for (int g = 0; g < 8; ++g) {
      float4_ sg = S[0] * mixp[g];
#pragma unroll
      for (int h = 1; h < 8; ++h) sg += S[h] * mixp[h*8 + g];
      float tm = fmaxf(fmaxf(sg[0], sg[1]), fmaxf(sg[2], sg[3]));
      float mn = fmaxf(m_[g], tm);
      l_[g] = l_[g]*__expf(m_[g]-mn) + __expf(sg[0]-mn) + __expf(sg[1]-mn)
            + __expf(sg[2]-mn) + __expf(sg[3]-mn);
      m_[g] = mn;
    }
  }
  // merge across the 4 lane-groups (same i, disjoint j)
#pragma unroll
  for (int g = 0; g < 8; ++g) {
#pragma unroll
    for (int off = 16; off < 64; off <<= 1) {
      float om = __shfl_xor(m_[g], off);
      float ol = __shfl_xor(l_[g], off);
      float mn = fmaxf(m_[g], om);
      l_[g] = l_[g]*__expf(m_[g]-mn) + ol*__expf(om-mn);
      m_[g] = mn;
    }
  }
  // merge across waves
  if (lgrp == 0) {
#pragma unroll
    for (int g = 0; g < 8; ++g) { Lm[w][g][lrow] = m_[g]; Ll[w][g][lrow] = l_[g]; }
  }
  __syncthreads();
  float mm[8];
#pragma unroll
  for (int g = 0; g < 8; ++g) {
    float M = Lm[0][g][lrow], L = Ll[0][g][lrow];
#pragma unroll
    for (int wv = 1; wv < 4; ++wv) {
      float om = Lm[wv][g][lrow], ol = Ll[wv][g][lrow];
      float mn = fmaxf(M, om);
      L = L*__expf(M-mn) + ol*__expf(om-mn);
      M = mn;
    }
    mm[g] = M + __logf(L);   // exp(s - mm) is exactly normalized
  }

  float4_ ot[8][4];
#pragma unroll
  for (int g = 0; g < 8; ++g)
#pragma unroll
    for (int dt = 0; dt < 4; ++dt) ot[g][dt] = (float4_){0.f,0.f,0.f,0.f};

  // ---------------- PASS 2: normalize + postmix + PV ----------------
  for (int jt = w; jt < 128; jt += 4) {
    int j0 = jt << 4;
    short8 kfr[8][2];
#pragma unroll
    for (int h = 0; h < 8; ++h) {
      int base = (((b<<3)+h)*2048 + j0 + lrow)*64 + lgrp*8;
      kfr[h][0] = *(const short8*)&Kb[base];
      kfr[h][1] = *(const short8*)&Kb[base + 32];
    }
    float4_ S[8];
#pragma unroll
    for (int h = 0; h < 8; ++h) {
      float4_ z = {0.f,0.f,0.f,0.f};
      z = __builtin_amdgcn_mfma_f32_16x16x32_bf16(kfr[h][0], qf[h][0], z, 0, 0, 0);
      S[h] = __builtin_amdgcn_mfma_f32_16x16x32_bf16(kfr[h][1], qf[h][1], z, 0, 0, 0);
    }
    half4 vf[8][4];
#pragma unroll
    for (int g = 0; g < 8; ++g) {
      int vbase = ((((b<<3)+g)<<6) + lrow)*2048 + j0 + lgrp*4;
#pragma unroll
      for (int dt = 0; dt < 4; ++dt) vf[g][dt] = *(const half4*)&Vt[vbase + dt*16*2048];
    }
    float4_ P[8];
#pragma unroll
    for (int g = 0; g < 8; ++g) {
      float4_ sg = S[0] * mixp[g];
#pragma unroll
      for (int h = 1; h < 8; ++h) sg += S[h] * mixp[h*8 + g];
      float4_ p;
      p[0] = __expf(sg[0] - mm[g]); p[1] = __expf(sg[1] - mm[g]);
      p[2] = __expf(sg[2] - mm[g]); p[3] = __expf(sg[3] - mm[g]);
      P[g] = p;
    }
#pragma unroll
    for (int g = 0; g < 8; ++g) {
      float4_ ag = P[0] * mixq[g];
#pragma unroll
      for (int h = 1; h < 8; ++h) ag += P[h] * mixq[h*8 + g];
      half4 pb;
      pb[0] = (_Float16)ag[0]; pb[1] = (_Float16)ag[1];
      pb[2] = (_Float16)ag[2]; pb[3] = (_Float16)ag[3];
#pragma unroll
      for (int dt = 0; dt < 4; ++dt)
        ot[g][dt] = __builtin_amdgcn_mfma_f32_16x16x16f16(vf[g][dt], pb, ot[g][dt], 0, 0, 0);
    }
  }

  // merge partial O across the 4 waves (disjoint j => sum)
#pragma unroll
  for (int wv = 0; wv < 4; ++wv) {
    if (w == wv) {
#pragma unroll
      for (int g = 0; g < 8; ++g)
#pragma unroll
        for (int dt = 0; dt < 4; ++dt)
#pragma unroll
          for (int r = 0; r < 4; ++r) {
            int d = dt*16 + lgrp*4 + r;
            if (wv == 0) Ob[g][d][lrow] = ot[g][dt][r];
            else         Ob[g][d][lrow] += ot[g][dt][r];
          }
    }
    __syncthreads();
  }
  // write AO (b, n, h*64+d) bf16
  int i = tid >> 4;
  int gd0 = (tid & 15) * 32;
  unsigned short* dst = &AO[(b*2048 + i0 + i)*512 + gd0];
  const float* ob = (const float*)Ob;
#pragma unroll
  for (int c = 0; c < 32; c += 8) {
    short8 pk;
#pragma unroll
    for (int e = 0; e < 8; ++e) pk[e] = (short)f2bf(ob[(gd0 + c + e)*16 + i]);
    *(short8*)&dst[c] = pk;
  }
}

// ---------------- out GEMM: AO(8192x512)bf16 @ Wout^T + bout -> fp32 ----------------
__global__ __launch_bounds__(256, 2) void out_gemm(
    const unsigned short* __restrict__ A, const unsigned short* __restrict__ Bt,
    const float* __restrict__ bout, float* __restrict__ out) {
  __shared__ unsigned short lA[128*32];
  __shared__ unsigned short lB[128*32];
  int bid = blockIdx.x;
  int tm = bid & 63, tn = bid >> 6;           // 64 x 4
  int m0 = tm * 128, n0 = tn * 128;
  int tid = threadIdx.x, lane = tid & 63, w = tid >> 6;
  int lrow = lane & 15, lgrp = lane >> 4;
  int wr = w >> 1, wc = w & 1;
  int r0 = tid >> 2, c0 = tid & 3;
  float4_ acc[4][4];
#pragma unroll
  for (int mi = 0; mi < 4; ++mi)
#pragma unroll
    for (int ni = 0; ni < 4; ++ni) acc[mi][ni] = (float4_){0.f,0.f,0.f,0.f};

  for (int k0 = 0; k0 < 512; k0 += 32) {
    short8 a0 = *(const short8*)&A[(m0 + r0)*512 + k0 + c0*8];
    short8 a1 = *(const short8*)&A[(m0 + 64 + r0)*512 + k0 + c0*8];
    short8 b0 = *(const short8*)&Bt[(n0 + r0)*512 + k0 + c0*8];
    short8 b1 = *(const short8*)&Bt[(n0 + 64 + r0)*512 + k0 + c0*8];
    __syncthreads();
    *(short8*)&lA[tid*8] = a0; *(short8*)&lA[(tid+256)*8] = a1;
    *(short8*)&lB[tid*8] = b0; *(short8*)&lB[(tid+256)*8] = b1;
    __syncthreads();
    short8 af[4], bfr[4];
#pragma unroll
    for (int mi = 0; mi < 4; ++mi) af[mi]  = *(const short8*)&lA[(wr*64 + mi*16 + lrow)*32 + lgrp*8];
#pragma unroll
    for (int ni = 0; ni < 4; ++ni) bfr[ni] = *(const short8*)&lB[(wc*64 + ni*16 + lrow)*32 + lgrp*8];
#pragma unroll
    for (int mi = 0; mi < 4; ++mi)
#pragma unroll
      for (int ni = 0; ni < 4; ++ni)
        acc[mi][ni] = __builtin_amdgcn_mfma_f32_16x16x32_bf16(af[mi], bfr[ni], acc[mi][ni], 0, 0, 0);
  }
#pragma unroll
  for (int mi = 0; mi < 4; ++mi)
#pragma unroll
    for (int ni = 0; ni < 4; ++ni) {
      int col = n0 + wc*64 + ni*16 + lrow;
      float bb = bout[col];
#pragma unroll
      for (int r = 0; r < 4; ++r) {
        int row = m0 + wr*64 + mi*16 + lgrp*4 + r;
        out[row*512 + col] = acc[mi][ni][r] + bb;
      }
    }
}

extern "C" void kernel_launch(void* const* d_in, const int* in_sizes, int n_in,
                              void* d_out, int out_size, void* d_ws, size_t ws_size,
                              hipStream_t stream) {
  (void)in_sizes; (void)n_in; (void)out_size; (void)ws_size;
  const float* x     = (const float*)d_in[0];
  const float* gamma = (const float*)d_in[1];
  const float* beta  = (const float*)d_in[2];
  const float* Wq    = (const float*)d_in[3];
  const float* Wkv   = (const float*)d_in[4];
  const float* mixp  = (const float*)d_in[5];
  const float* mixq  = (const float*)d_in[6];
  const float* Wout  = (const float*)d_in[7];
  const float* bout  = (const float*)d_in[8];
  float* out = (float*)d_out;

  unsigned short* xn  = (unsigned short*)d_ws;      // 8192*512
  unsigned short* wt  = xn  + 4194304;              // 1536*512
  unsigned short* wot = wt  + 786432;               // 512*512
  unsigned short* Qs  = wot + 262144;               // (b,h,n,64) bf16
  unsigned short* Kb  = Qs  + 4194304;              // (b,h,n,64) bf16
  _Float16*       Vt  = (_Float16*)(Kb + 4194304);  // (b,h,64,n) f16
  unsigned short* AO  = (unsigned short*)(Vt + 4194304); // (b,n,512) bf16

  ln_kernel<<<2048, 256, 0, stream>>>(x, gamma, beta, xn);
  wconv<<<4096, 256, 0, stream>>>(Wq, Wkv, Wout, wt, wot);
  qkv_gemm<<<768, 256, 0, stream>>>(xn, wt, Qs, Kb, Vt);
  attn_kernel<<<512, 256, 0, stream>>>(Qs, Kb, Vt, mixp, mixq, AO);
  out_gemm<<<256, 256, 0, stream>>>(AO, wot, bout, out);
}